// Round 9
// baseline (231.325 us; speedup 1.0000x reference)
//
#include <hip/hip_runtime.h>
#include <hip/hip_bf16.h>
#include <math.h>
#include <stdint.h>

typedef __bf16 bf16;
typedef __bf16 bf16x8 __attribute__((ext_vector_type(8)));
typedef __bf16 bf16x4 __attribute__((ext_vector_type(4)));
typedef float  f32x4  __attribute__((ext_vector_type(4)));

#define MFMA16(a,b,c) __builtin_amdgcn_mfma_f32_16x16x32_bf16((a),(b),(c),0,0,0)

static constexpr int kB  = 2;
static constexpr int kS  = 2048;
static constexpr int kD  = 1024;
static constexpr int kH  = 16;
static constexpr int kHD = 64;
static constexpr int kM  = kB * kS;         // 4096
// exp(s*0.125) = exp2(s * 0.125 * log2(e)) ; folded into Q at proj epilogue
static constexpr float kExpC = 0.125f * 1.44269504f;

// ---------------- fp32 -> bf16 conversion (x + 4 weights) + RoPE table ----------------
__global__ void cvt_all(const float* __restrict__ x,
                        const float* __restrict__ wq, const float* __restrict__ wk,
                        const float* __restrict__ wv, const float* __restrict__ wo,
                        bf16* __restrict__ xb,
                        bf16* __restrict__ wqb, bf16* __restrict__ wkb,
                        bf16* __restrict__ wvb, bf16* __restrict__ wob,
                        float2* __restrict__ rtab)
{
  const int i = blockIdx.x * 256 + threadIdx.x;   // float4 index
  const int NX4 = (kM * kD) / 4;                  // 1048576
  const int NW4 = (kD * kD) / 4;                  // 262144 = 2^18
  if (i >= NX4 + 4 * NW4) {                       // RoPE cos/sin table: 2048 x 32
    const int idx = i - (NX4 + 4 * NW4);          // exactly 65536 of these
    const int s = idx >> 5, d = idx & 31;
    const float f = exp2f(-(float)d * 0.4152410118609203f);  // 10000^(-d/32)
    float sn, cs;
    sincosf((float)s * f, &sn, &cs);
    rtab[idx] = make_float2(cs, sn);
    return;
  }
  const float* src; bf16* dst; int off;
  if (i < NX4) { src = x; dst = xb; off = i; }
  else {
    const int j = i - NX4;
    const int seg = j >> 18;
    off = j & (NW4 - 1);
    src = (seg == 0) ? wq : (seg == 1) ? wk : (seg == 2) ? wv : wo;
    dst = (seg == 0) ? wqb : (seg == 1) ? wkb : (seg == 2) ? wvb : wob;
  }
  const float4 v = ((const float4*)src)[off];
  bf16x4 o = { (bf16)v.x, (bf16)v.y, (bf16)v.z, (bf16)v.w };
  ((bf16x4*)dst)[off] = o;
}

// ---------------- 128x128 tile bf16 GEMM core, register-pipelined staging ----------------
// C = A * B^T. A:[M,K], Bw:[N,K], row-major bf16. BK=32, 256 threads, 2x2 waves.
// Staging goes global->VGPR (prefetched one tile ahead; loads stay in flight
// across s_barrier since they are wave-private) then VGPR->LDS after the barrier.
__device__ __forceinline__ void gemm_core_128(
    const bf16* __restrict__ A, const bf16* __restrict__ Bw,
    int m0, int n0, int K, bf16* aT, bf16* bT, f32x4 acc[4][4])
{
  const int t = threadIdx.x, lane = t & 63, wave = t >> 6;
  const int wm = wave >> 1, wn = wave & 1;
  const int srow = lane >> 2;          // 0..15
  const int scol = (lane & 3) * 8;     // 0,8,16,24
  const bf16* ga0 = A  + (size_t)(m0 + wave * 16 + srow) * K + scol;
  const bf16* ga1 = ga0 + (size_t)64 * K;
  const bf16* gb0 = Bw + (size_t)(n0 + wave * 16 + srow) * K + scol;
  const bf16* gb1 = gb0 + (size_t)64 * K;
  bf16* const wa0 = aT + wave * 512 + lane * 8;
  bf16* const wb0 = bT + wave * 512 + lane * 8;

  bf16x8 ra0 = *(const bf16x8*)ga0;
  bf16x8 ra1 = *(const bf16x8*)ga1;
  bf16x8 rb0 = *(const bf16x8*)gb0;
  bf16x8 rb1 = *(const bf16x8*)gb1;

  for (int k0 = 0; k0 < K; k0 += 32) {
    const int kn = (k0 + 32 < K) ? (k0 + 32) : 0;   // last prefetch discarded
    const bf16x8 na0 = *(const bf16x8*)(ga0 + kn);
    const bf16x8 na1 = *(const bf16x8*)(ga1 + kn);
    const bf16x8 nb0 = *(const bf16x8*)(gb0 + kn);
    const bf16x8 nb1 = *(const bf16x8*)(gb1 + kn);
    __syncthreads();                   // prior tile's readers done
    *(bf16x8*)wa0 = ra0;  *(bf16x8*)(wa0 + 2048) = ra1;
    *(bf16x8*)wb0 = rb0;  *(bf16x8*)(wb0 + 2048) = rb1;
    __syncthreads();                   // tile visible
    bf16x8 af[4], bfr[4];
#pragma unroll
    for (int i = 0; i < 4; ++i) {
      af[i]  = *(const bf16x8*)(aT + (wm * 64 + i * 16 + (lane & 15)) * 32 + (lane >> 4) * 8);
      bfr[i] = *(const bf16x8*)(bT + (wn * 64 + i * 16 + (lane & 15)) * 32 + (lane >> 4) * 8);
    }
#pragma unroll
    for (int i = 0; i < 4; ++i)
#pragma unroll
      for (int j = 0; j < 4; ++j)
        acc[i][j] = MFMA16(af[i], bfr[j], acc[i][j]);
    ra0 = na0; ra1 = na1; rb0 = nb0; rb1 = nb1;
  }
}

// ---------------- QKV projection + RoPE epilogue; V written pre-transposed ----------------
__global__ __launch_bounds__(256) void proj_qkv(
    const bf16* __restrict__ xb,
    const bf16* __restrict__ wqb, const bf16* __restrict__ wkb, const bf16* __restrict__ wvb,
    bf16* __restrict__ Qb, bf16* __restrict__ Kb, bf16* __restrict__ Vt,
    const float2* __restrict__ rtab)
{
  __shared__ __align__(16) bf16 aT[4096];
  __shared__ __align__(16) bf16 bT[4096];
  __shared__ __align__(16) bf16 vtr[2 * 64 * 136];   // z==2 only: [head][d][s+pad]
  const int z = blockIdx.z;
  const bf16* Ww = (z == 0) ? wqb : (z == 1) ? wkb : wvb;
  const int m0 = blockIdx.x * 128, n0 = blockIdx.y * 128;
  f32x4 acc[4][4] = {};
  gemm_core_128(xb, Ww, m0, n0, kD, aT, bT, acc);

  const int lane = threadIdx.x & 63, wave = threadIdx.x >> 6;
  const int wm = wave >> 1, wn = wave & 1, quad = lane >> 4, lc = lane & 15;
  const int hh = (n0 >> 6) + wn;     // head index; wave's 64-col span == one head
  if (z == 2) {                      // V: transpose via LDS, store [bh][d][s] coalesced
#pragma unroll
    for (int i = 0; i < 4; ++i)
#pragma unroll
      for (int j = 0; j < 4; ++j) {
        bf16x4 p;
#pragma unroll
        for (int r = 0; r < 4; ++r) p[r] = (bf16)acc[i][j][r];
        *(bf16x4*)&vtr[(wn * 64 + j * 16 + lc) * 136 + wm * 64 + i * 16 + quad * 4] = p;
      }
    __syncthreads();
    const int t = threadIdx.x;
    const int row = t >> 1;          // head*64 + d, 0..127
    const int sh = (t & 1) * 64;
    const int bidx = m0 >> 11;
    const int hh2 = (n0 >> 6) + (row >> 6);
    const int d = row & 63;
    bf16* dst = Vt + ((size_t)(bidx * kH + hh2) * kHD + d) * kS + (m0 & 2047) + sh;
#pragma unroll
    for (int u = 0; u < 8; ++u)
      *(uint4*)(dst + u * 8) = *(const uint4*)&vtr[row * 136 + sh + u * 8];
  } else {                           // Q/K: RoPE in-register (pair d with d+32)
    bf16* Op = (z == 0) ? Qb : Kb;
    const float f = (z == 0) ? kExpC : 1.0f;   // fold softmax scale into Q
#pragma unroll
    for (int j = 0; j < 2; ++j) {
      const int d = j * 16 + lc;     // 0..31
#pragma unroll
      for (int i = 0; i < 4; ++i)
#pragma unroll
        for (int r = 0; r < 4; ++r) {
          const int m = m0 + wm * 64 + i * 16 + quad * 4 + r;
          const int bidx = m >> 11, s = m & 2047;
          const float2 cs = rtab[s * 32 + d];
          const float v0 = acc[i][j][r], v1 = acc[i][j + 2][r];
          bf16* dst = Op + ((size_t)(bidx * kH + hh) * kS + s) * kHD;
          dst[d]      = (bf16)((v0 * cs.x - v1 * cs.y) * f);
          dst[d + 32] = (bf16)((v1 * cs.x + v0 * cs.y) * f);
        }
    }
  }
}

// ---------------- flash attention: S^T trick + register-resident P + prefetch ----------------
// Grid is 1-D 512 with an XCD-aware decode: all 16 q-tiles of a head land on
// one XCD so its K/V stay in that XCD's 4 MB L2.
// LDS: kT [key=128][d=64] stride 72; vT [d=64][key=128] stride 136. 35840 B.
__global__ __launch_bounds__(256, 2) void attn(
    const bf16* __restrict__ Qb, const bf16* __restrict__ Kb,
    const bf16* __restrict__ Vt, bf16* __restrict__ Ob)
{
  __shared__ __align__(16) bf16 kT[128 * 72];
  __shared__ __align__(16) bf16 vT[64 * 136];
  const int t = threadIdx.x, lane = t & 63, wave = t >> 6;
  const int quad = lane >> 4, lc = lane & 15;
  const int bid = blockIdx.x;
  const int qt = (bid >> 3) & 15;
  const int bh = (bid & 7) * 4 + (bid >> 7);     // XCD-locality decode
  const size_t base = (size_t)bh * kS * kHD;
  const bf16* Qp = Qb + base + (size_t)qt * 128 * kHD;
  const bf16* Kp = Kb + base;
  const bf16* Vp = Vt + base;                     // [d][s]

  // Q fragments (B-operand layout), in registers for the whole kernel
  bf16x8 qf[2][2];
#pragma unroll
  for (int tm = 0; tm < 2; ++tm)
#pragma unroll
    for (int ks = 0; ks < 2; ++ks)
      qf[tm][ks] = *(const bf16x8*)(Qp + (wave * 32 + tm * 16 + lc) * kHD + ks * 32 + quad * 8);

  f32x4 oacc[2][4] = {};
  f32x4 lacc[2] = {};
  const bf16 one = (bf16)1.0f;
  const bf16x8 ones = { one, one, one, one, one, one, one, one };

  // staging: K: 2 threads/row, 64 B each. V^T: thread (d=t>>2, c=t&3), 64 B each.
  const int srow = t >> 1, shalf = (t & 1) * 32;
  const int vd = t >> 2, vc = t & 3;

  // prologue: tile 0 into registers
  uint4 rk[4], rv[4];
  {
    const bf16* ksrc = Kp + (size_t)srow * kHD + shalf;
    const bf16* vsrc = Vp + (size_t)vd * kS + vc * 32;
#pragma unroll
    for (int u = 0; u < 4; ++u) rk[u] = ((const uint4*)ksrc)[u];
#pragma unroll
    for (int u = 0; u < 4; ++u) rv[u] = ((const uint4*)vsrc)[u];
  }

  for (int kt = 0; kt < kS / 128; ++kt) {
    __syncthreads();
#pragma unroll
    for (int u = 0; u < 4; ++u)
      *(uint4*)&kT[srow * 72 + shalf + u * 8] = rk[u];
#pragma unroll
    for (int u = 0; u < 4; ++u)
      *(uint4*)&vT[vd * 136 + vc * 32 + u * 8] = rv[u];
    __syncthreads();

    // prefetch next tile into registers (in flight across the compute phase)
    const int ktn = (kt + 1 < kS / 128) ? kt + 1 : 0;
    uint4 nk_[4], nv_[4];
    {
      const bf16* ksrc = Kp + (size_t)(ktn * 128 + srow) * kHD + shalf;
      const bf16* vsrc = Vp + (size_t)vd * kS + ktn * 128 + vc * 32;
#pragma unroll
      for (int u = 0; u < 4; ++u) nk_[u] = ((const uint4*)ksrc)[u];
#pragma unroll
      for (int u = 0; u < 4; ++u) nv_[u] = ((const uint4*)vsrc)[u];
    }

    // K fragments for the whole tile
    bf16x8 kf[8][2];
#pragma unroll
    for (int nk = 0; nk < 8; ++nk)
#pragma unroll
      for (int ks = 0; ks < 2; ++ks)
        kf[nk][ks] = *(const bf16x8*)&kT[(nk * 16 + lc) * 72 + ks * 32 + quad * 8];

    // S^T = K Q^T ; p = exp2(s) packed straight into A-fragments (no LDS!)
    bf16x8 pfrag[2][4];
#pragma unroll
    for (int tm = 0; tm < 2; ++tm) {
      f32x4 sc[8] = {};
#pragma unroll
      for (int nk = 0; nk < 8; ++nk) {
        sc[nk] = MFMA16(kf[nk][0], qf[tm][0], sc[nk]);
        sc[nk] = MFMA16(kf[nk][1], qf[tm][1], sc[nk]);
      }
#pragma unroll
      for (int kp = 0; kp < 4; ++kp) {
        bf16x8 p;
#pragma unroll
        for (int j = 0; j < 4; ++j) {
          p[j]     = (bf16)__builtin_amdgcn_exp2f(sc[2 * kp][j]);
          p[j + 4] = (bf16)__builtin_amdgcn_exp2f(sc[2 * kp + 1][j]);
        }
        pfrag[tm][kp] = p;
      }
    }

    // row sums via ones-MFMA (same remapped key order on both operands)
#pragma unroll
    for (int kp = 0; kp < 4; ++kp)
#pragma unroll
      for (int tm = 0; tm < 2; ++tm)
        lacc[tm] = MFMA16(pfrag[tm][kp], ones, lacc[tm]);

    // O += P V : V fragment = two b64 reads matching the remapped key order
#pragma unroll
    for (int nd = 0; nd < 4; ++nd)
#pragma unroll
      for (int kp = 0; kp < 4; ++kp) {
        const bf16x4 lo = *(const bf16x4*)&vT[(nd * 16 + lc) * 136 + kp * 32 + quad * 4];
        const bf16x4 hi = *(const bf16x4*)&vT[(nd * 16 + lc) * 136 + kp * 32 + 16 + quad * 4];
        const bf16x8 vfr = __builtin_shufflevector(lo, hi, 0, 1, 2, 3, 4, 5, 6, 7);
#pragma unroll
        for (int tm = 0; tm < 2; ++tm)
          oacc[tm][nd] = MFMA16(pfrag[tm][kp], vfr, oacc[tm][nd]);
      }

#pragma unroll
    for (int u = 0; u < 4; ++u) { rk[u] = nk_[u]; rv[u] = nv_[u]; }
  }

  // normalize + store O as bf16 in [B,S,D] layout for the output GEMM
  const int b = bh >> 4, h = bh & 15;
#pragma unroll
  for (int tm = 0; tm < 2; ++tm)
#pragma unroll
    for (int r = 0; r < 4; ++r) {
      const float inv = 1.0f / lacc[tm][r];
      const int s = qt * 128 + wave * 32 + tm * 16 + quad * 4 + r;
      bf16* dst = Ob + ((size_t)(b * kS + s)) * kD + h * kHD;
#pragma unroll
      for (int nd = 0; nd < 4; ++nd)
        dst[nd * 16 + lc] = (bf16)(oacc[tm][nd][r] * inv);
    }
}

// ---------------- output projection (fp32 epilogue) ----------------
__global__ __launch_bounds__(256) void out_proj(
    const bf16* __restrict__ Ab, const bf16* __restrict__ wob, float* __restrict__ Cout)
{
  __shared__ __align__(16) bf16 aT[4096];
  __shared__ __align__(16) bf16 bT[4096];
  const int m0 = blockIdx.x * 128, n0 = blockIdx.y * 128;
  f32x4 acc[4][4] = {};
  gemm_core_128(Ab, wob, m0, n0, kD, aT, bT, acc);
  const int lane = threadIdx.x & 63, wave = threadIdx.x >> 6;
  const int wm = wave >> 1, wn = wave & 1, quad = lane >> 4, lc = lane & 15;
#pragma unroll
  for (int i = 0; i < 4; ++i)
#pragma unroll
    for (int r = 0; r < 4; ++r) {
      const int m = m0 + wm * 64 + i * 16 + quad * 4 + r;
#pragma unroll
      for (int j = 0; j < 4; ++j)
        Cout[(size_t)m * kD + n0 + wn * 64 + j * 16 + lc] = acc[i][j][r];
    }
}

extern "C" void kernel_launch(void* const* d_in, const int* in_sizes, int n_in,
                              void* d_out, int out_size, void* d_ws, size_t ws_size,
                              hipStream_t stream)
{
  const float* x  = (const float*)d_in[0];
  const float* wq = (const float*)d_in[1];
  const float* wk = (const float*)d_in[2];
  const float* wv = (const float*)d_in[3];
  const float* wo = (const float*)d_in[4];
  float* out = (float*)d_out;

  char* ws = (char*)d_ws;
  const size_t MB = 1024 * 1024;
  if (ws_size < 57 * MB) return;
  bf16* xb  = (bf16*)(ws + 0 * MB);   // 8 MB
  bf16* wqb = (bf16*)(ws + 8 * MB);   // 2 MB each
  bf16* wkb = (bf16*)(ws + 10 * MB);
  bf16* wvb = (bf16*)(ws + 12 * MB);
  bf16* wob = (bf16*)(ws + 14 * MB);
  bf16* Qb  = (bf16*)(ws + 16 * MB);  // 8 MB each, [B*H][S][64]
  bf16* Kb  = (bf16*)(ws + 24 * MB);
  bf16* Ob  = (bf16*)(ws + 40 * MB);  // 8 MB, [B,S,D]
  float2* rtab = (float2*)(ws + 48 * MB);  // 512 KB RoPE table
  bf16* Vtp = (bf16*)(ws + 49 * MB);  // 8 MB, V transposed [B*H][64][S]

  cvt_all<<<8448, 256, 0, stream>>>(x, wq, wk, wv, wo, xb, wqb, wkb, wvb, wob, rtab);
  proj_qkv<<<dim3(32, 8, 3), 256, 0, stream>>>(xb, wqb, wkb, wvb, Qb, Kb, Vtp, rtab);
  attn<<<dim3(512), 256, 0, stream>>>(Qb, Kb, Vtp, Ob);
  out_proj<<<dim3(32, 8), 256, 0, stream>>>(Ob, wob, out);
}

// Round 10
// 180.450 us; speedup vs baseline: 1.2819x; 1.2819x over previous
//
#include <hip/hip_runtime.h>
#include <hip/hip_bf16.h>
#include <math.h>
#include <stdint.h>

typedef __bf16 bf16;
typedef __bf16 bf16x8 __attribute__((ext_vector_type(8)));
typedef __bf16 bf16x4 __attribute__((ext_vector_type(4)));
typedef float  f32x4  __attribute__((ext_vector_type(4)));

#define MFMA16(a,b,c) __builtin_amdgcn_mfma_f32_16x16x32_bf16((a),(b),(c),0,0,0)

static constexpr int kB  = 2;
static constexpr int kS  = 2048;
static constexpr int kD  = 1024;
static constexpr int kH  = 16;
static constexpr int kHD = 64;
static constexpr int kM  = kB * kS;         // 4096
// exp(s*0.125) = exp2(s * 0.125 * log2(e)) ; folded into Q at proj epilogue
static constexpr float kExpC = 0.125f * 1.44269504f;

// ---------------- fp32 -> bf16 conversion (x + 4 weights) + RoPE table ----------------
__global__ void cvt_all(const float* __restrict__ x,
                        const float* __restrict__ wq, const float* __restrict__ wk,
                        const float* __restrict__ wv, const float* __restrict__ wo,
                        bf16* __restrict__ xb,
                        bf16* __restrict__ wqb, bf16* __restrict__ wkb,
                        bf16* __restrict__ wvb, bf16* __restrict__ wob,
                        float2* __restrict__ rtab)
{
  const int i = blockIdx.x * 256 + threadIdx.x;   // float4 index
  const int NX4 = (kM * kD) / 4;                  // 1048576
  const int NW4 = (kD * kD) / 4;                  // 262144 = 2^18
  if (i >= NX4 + 4 * NW4) {                       // RoPE cos/sin table: 2048 x 32
    const int idx = i - (NX4 + 4 * NW4);          // exactly 65536 of these
    const int s = idx >> 5, d = idx & 31;
    const float f = exp2f(-(float)d * 0.4152410118609203f);  // 10000^(-d/32)
    float sn, cs;
    sincosf((float)s * f, &sn, &cs);
    rtab[idx] = make_float2(cs, sn);
    return;
  }
  const float* src; bf16* dst; int off;
  if (i < NX4) { src = x; dst = xb; off = i; }
  else {
    const int j = i - NX4;
    const int seg = j >> 18;
    off = j & (NW4 - 1);
    src = (seg == 0) ? wq : (seg == 1) ? wk : (seg == 2) ? wv : wo;
    dst = (seg == 0) ? wqb : (seg == 1) ? wkb : (seg == 2) ? wvb : wob;
  }
  const float4 v = ((const float4*)src)[off];
  bf16x4 o = { (bf16)v.x, (bf16)v.y, (bf16)v.z, (bf16)v.w };
  ((bf16x4*)dst)[off] = o;
}

// ---------------- 128x128 tile bf16 GEMM core, register-pipelined staging ----------------
// C = A * B^T. A:[M,K], Bw:[N,K], row-major bf16. BK=32, 256 threads, 2x2 waves.
// Staging goes global->VGPR (prefetched one tile ahead; loads stay in flight
// across s_barrier since they are wave-private) then VGPR->LDS after the barrier.
// Kept from round 9: proj_qkv ~50 -> ~32 us (inferred). attn must NOT use this
// pattern: its larger live state made the same trick spill (round 9: 103 MB
// scratch writes, attn 2x slower).
__device__ __forceinline__ void gemm_core_128(
    const bf16* __restrict__ A, const bf16* __restrict__ Bw,
    int m0, int n0, int K, bf16* aT, bf16* bT, f32x4 acc[4][4])
{
  const int t = threadIdx.x, lane = t & 63, wave = t >> 6;
  const int wm = wave >> 1, wn = wave & 1;
  const int srow = lane >> 2;          // 0..15
  const int scol = (lane & 3) * 8;     // 0,8,16,24
  const bf16* ga0 = A  + (size_t)(m0 + wave * 16 + srow) * K + scol;
  const bf16* ga1 = ga0 + (size_t)64 * K;
  const bf16* gb0 = Bw + (size_t)(n0 + wave * 16 + srow) * K + scol;
  const bf16* gb1 = gb0 + (size_t)64 * K;
  bf16* const wa0 = aT + wave * 512 + lane * 8;
  bf16* const wb0 = bT + wave * 512 + lane * 8;

  bf16x8 ra0 = *(const bf16x8*)ga0;
  bf16x8 ra1 = *(const bf16x8*)ga1;
  bf16x8 rb0 = *(const bf16x8*)gb0;
  bf16x8 rb1 = *(const bf16x8*)gb1;

  for (int k0 = 0; k0 < K; k0 += 32) {
    const int kn = (k0 + 32 < K) ? (k0 + 32) : 0;   // last prefetch discarded
    const bf16x8 na0 = *(const bf16x8*)(ga0 + kn);
    const bf16x8 na1 = *(const bf16x8*)(ga1 + kn);
    const bf16x8 nb0 = *(const bf16x8*)(gb0 + kn);
    const bf16x8 nb1 = *(const bf16x8*)(gb1 + kn);
    __syncthreads();                   // prior tile's readers done
    *(bf16x8*)wa0 = ra0;  *(bf16x8*)(wa0 + 2048) = ra1;
    *(bf16x8*)wb0 = rb0;  *(bf16x8*)(wb0 + 2048) = rb1;
    __syncthreads();                   // tile visible
    bf16x8 af[4], bfr[4];
#pragma unroll
    for (int i = 0; i < 4; ++i) {
      af[i]  = *(const bf16x8*)(aT + (wm * 64 + i * 16 + (lane & 15)) * 32 + (lane >> 4) * 8);
      bfr[i] = *(const bf16x8*)(bT + (wn * 64 + i * 16 + (lane & 15)) * 32 + (lane >> 4) * 8);
    }
#pragma unroll
    for (int i = 0; i < 4; ++i)
#pragma unroll
      for (int j = 0; j < 4; ++j)
        acc[i][j] = MFMA16(af[i], bfr[j], acc[i][j]);
    ra0 = na0; ra1 = na1; rb0 = nb0; rb1 = nb1;
  }
}

// ---------------- QKV projection + RoPE epilogue; V written pre-transposed ----------------
__global__ __launch_bounds__(256) void proj_qkv(
    const bf16* __restrict__ xb,
    const bf16* __restrict__ wqb, const bf16* __restrict__ wkb, const bf16* __restrict__ wvb,
    bf16* __restrict__ Qb, bf16* __restrict__ Kb, bf16* __restrict__ Vt,
    const float2* __restrict__ rtab)
{
  __shared__ __align__(16) bf16 aT[4096];
  __shared__ __align__(16) bf16 bT[4096];
  __shared__ __align__(16) bf16 vtr[2 * 64 * 136];   // z==2 only: [head][d][s+pad]
  const int z = blockIdx.z;
  const bf16* Ww = (z == 0) ? wqb : (z == 1) ? wkb : wvb;
  const int m0 = blockIdx.x * 128, n0 = blockIdx.y * 128;
  f32x4 acc[4][4] = {};
  gemm_core_128(xb, Ww, m0, n0, kD, aT, bT, acc);

  const int lane = threadIdx.x & 63, wave = threadIdx.x >> 6;
  const int wm = wave >> 1, wn = wave & 1, quad = lane >> 4, lc = lane & 15;
  const int hh = (n0 >> 6) + wn;     // head index; wave's 64-col span == one head
  if (z == 2) {                      // V: transpose via LDS, store [bh][d][s] coalesced
#pragma unroll
    for (int i = 0; i < 4; ++i)
#pragma unroll
      for (int j = 0; j < 4; ++j) {
        bf16x4 p;
#pragma unroll
        for (int r = 0; r < 4; ++r) p[r] = (bf16)acc[i][j][r];
        *(bf16x4*)&vtr[(wn * 64 + j * 16 + lc) * 136 + wm * 64 + i * 16 + quad * 4] = p;
      }
    __syncthreads();
    const int t = threadIdx.x;
    const int row = t >> 1;          // head*64 + d, 0..127
    const int sh = (t & 1) * 64;
    const int bidx = m0 >> 11;
    const int hh2 = (n0 >> 6) + (row >> 6);
    const int d = row & 63;
    bf16* dst = Vt + ((size_t)(bidx * kH + hh2) * kHD + d) * kS + (m0 & 2047) + sh;
#pragma unroll
    for (int u = 0; u < 8; ++u)
      *(uint4*)(dst + u * 8) = *(const uint4*)&vtr[row * 136 + sh + u * 8];
  } else {                           // Q/K: RoPE in-register (pair d with d+32)
    bf16* Op = (z == 0) ? Qb : Kb;
    const float f = (z == 0) ? kExpC : 1.0f;   // fold softmax scale into Q
#pragma unroll
    for (int j = 0; j < 2; ++j) {
      const int d = j * 16 + lc;     // 0..31
#pragma unroll
      for (int i = 0; i < 4; ++i)
#pragma unroll
        for (int r = 0; r < 4; ++r) {
          const int m = m0 + wm * 64 + i * 16 + quad * 4 + r;
          const int bidx = m >> 11, s = m & 2047;
          const float2 cs = rtab[s * 32 + d];
          const float v0 = acc[i][j][r], v1 = acc[i][j + 2][r];
          bf16* dst = Op + ((size_t)(bidx * kH + hh) * kS + s) * kHD;
          dst[d]      = (bf16)((v0 * cs.x - v1 * cs.y) * f);
          dst[d + 32] = (bf16)((v1 * cs.x + v0 * cs.y) * f);
        }
    }
  }
}

// ---------------- flash attention: S^T trick + register-resident P ----------------
// Grid is 1-D 512 with an XCD-aware decode: all 16 q-tiles of a head land on
// one XCD so its K/V stay in that XCD's 4 MB L2.
// Staging loads/writes stay inside the barrier phase: the cross-phase register
// prefetch variant spilled (round 9) — do not reintroduce it.
// LDS: kT [key=128][d=64] stride 72; vT [d=64][key=128] stride 136. 35840 B.
__global__ __launch_bounds__(256, 2) void attn(
    const bf16* __restrict__ Qb, const bf16* __restrict__ Kb,
    const bf16* __restrict__ Vt, bf16* __restrict__ Ob)
{
  __shared__ __align__(16) bf16 kT[128 * 72];
  __shared__ __align__(16) bf16 vT[64 * 136];
  const int t = threadIdx.x, lane = t & 63, wave = t >> 6;
  const int quad = lane >> 4, lc = lane & 15;
  const int bid = blockIdx.x;
  const int qt = (bid >> 3) & 15;
  const int bh = (bid & 7) * 4 + (bid >> 7);     // XCD-locality decode
  const size_t base = (size_t)bh * kS * kHD;
  const bf16* Qp = Qb + base + (size_t)qt * 128 * kHD;
  const bf16* Kp = Kb + base;
  const bf16* Vp = Vt + base;                     // [d][s]

  // Q fragments (B-operand layout), in registers for the whole kernel
  bf16x8 qf[2][2];
#pragma unroll
  for (int tm = 0; tm < 2; ++tm)
#pragma unroll
    for (int ks = 0; ks < 2; ++ks)
      qf[tm][ks] = *(const bf16x8*)(Qp + (wave * 32 + tm * 16 + lc) * kHD + ks * 32 + quad * 8);

  f32x4 oacc[2][4] = {};
  f32x4 lacc[2] = {};
  const bf16 one = (bf16)1.0f;
  const bf16x8 ones = { one, one, one, one, one, one, one, one };

  // staging: K: 2 threads/row, 64 B each. V^T: thread (d=t>>2, c=t&3), 64 B each.
  const int srow = t >> 1, shalf = (t & 1) * 32;
  const int vd = t >> 2, vc = t & 3;

  for (int kt = 0; kt < kS / 128; ++kt) {
    __syncthreads();
    {
      const bf16* ksrc = Kp + (size_t)(kt * 128 + srow) * kHD + shalf;
#pragma unroll
      for (int u = 0; u < 4; ++u)
        *(uint4*)&kT[srow * 72 + shalf + u * 8] = *(const uint4*)(ksrc + u * 8);
      const bf16* vsrc = Vp + (size_t)vd * kS + kt * 128 + vc * 32;
#pragma unroll
      for (int u = 0; u < 4; ++u)
        *(uint4*)&vT[vd * 136 + vc * 32 + u * 8] = *(const uint4*)(vsrc + u * 8);
    }
    __syncthreads();

    // K fragments for the whole tile
    bf16x8 kf[8][2];
#pragma unroll
    for (int nk = 0; nk < 8; ++nk)
#pragma unroll
      for (int ks = 0; ks < 2; ++ks)
        kf[nk][ks] = *(const bf16x8*)&kT[(nk * 16 + lc) * 72 + ks * 32 + quad * 8];

    // S^T = K Q^T ; p = exp2(s) packed straight into A-fragments (no LDS!)
    bf16x8 pfrag[2][4];
#pragma unroll
    for (int tm = 0; tm < 2; ++tm) {
      f32x4 sc[8] = {};
#pragma unroll
      for (int nk = 0; nk < 8; ++nk) {
        sc[nk] = MFMA16(kf[nk][0], qf[tm][0], sc[nk]);
        sc[nk] = MFMA16(kf[nk][1], qf[tm][1], sc[nk]);
      }
#pragma unroll
      for (int kp = 0; kp < 4; ++kp) {
        bf16x8 p;
#pragma unroll
        for (int j = 0; j < 4; ++j) {
          p[j]     = (bf16)__builtin_amdgcn_exp2f(sc[2 * kp][j]);
          p[j + 4] = (bf16)__builtin_amdgcn_exp2f(sc[2 * kp + 1][j]);
        }
        pfrag[tm][kp] = p;
      }
    }

    // row sums via ones-MFMA (same remapped key order on both operands)
#pragma unroll
    for (int kp = 0; kp < 4; ++kp)
#pragma unroll
      for (int tm = 0; tm < 2; ++tm)
        lacc[tm] = MFMA16(pfrag[tm][kp], ones, lacc[tm]);

    // O += P V : V fragment = two b64 reads matching the remapped key order
#pragma unroll
    for (int nd = 0; nd < 4; ++nd)
#pragma unroll
      for (int kp = 0; kp < 4; ++kp) {
        const bf16x4 lo = *(const bf16x4*)&vT[(nd * 16 + lc) * 136 + kp * 32 + quad * 4];
        const bf16x4 hi = *(const bf16x4*)&vT[(nd * 16 + lc) * 136 + kp * 32 + 16 + quad * 4];
        const bf16x8 vfr = __builtin_shufflevector(lo, hi, 0, 1, 2, 3, 4, 5, 6, 7);
#pragma unroll
        for (int tm = 0; tm < 2; ++tm)
          oacc[tm][nd] = MFMA16(pfrag[tm][kp], vfr, oacc[tm][nd]);
      }
  }

  // normalize + store O as bf16 in [B,S,D] layout for the output GEMM
  const int b = bh >> 4, h = bh & 15;
#pragma unroll
  for (int tm = 0; tm < 2; ++tm)
#pragma unroll
    for (int r = 0; r < 4; ++r) {
      const float inv = 1.0f / lacc[tm][r];
      const int s = qt * 128 + wave * 32 + tm * 16 + quad * 4 + r;
      bf16* dst = Ob + ((size_t)(b * kS + s)) * kD + h * kHD;
#pragma unroll
      for (int nd = 0; nd < 4; ++nd)
        dst[nd * 16 + lc] = (bf16)(oacc[tm][nd][r] * inv);
    }
}

// ---------------- output projection (fp32 epilogue) ----------------
__global__ __launch_bounds__(256) void out_proj(
    const bf16* __restrict__ Ab, const bf16* __restrict__ wob, float* __restrict__ Cout)
{
  __shared__ __align__(16) bf16 aT[4096];
  __shared__ __align__(16) bf16 bT[4096];
  const int m0 = blockIdx.x * 128, n0 = blockIdx.y * 128;
  f32x4 acc[4][4] = {};
  gemm_core_128(Ab, wob, m0, n0, kD, aT, bT, acc);
  const int lane = threadIdx.x & 63, wave = threadIdx.x >> 6;
  const int wm = wave >> 1, wn = wave & 1, quad = lane >> 4, lc = lane & 15;
#pragma unroll
  for (int i = 0; i < 4; ++i)
#pragma unroll
    for (int r = 0; r < 4; ++r) {
      const int m = m0 + wm * 64 + i * 16 + quad * 4 + r;
#pragma unroll
      for (int j = 0; j < 4; ++j)
        Cout[(size_t)m * kD + n0 + wn * 64 + j * 16 + lc] = acc[i][j][r];
    }
}

extern "C" void kernel_launch(void* const* d_in, const int* in_sizes, int n_in,
                              void* d_out, int out_size, void* d_ws, size_t ws_size,
                              hipStream_t stream)
{
  const float* x  = (const float*)d_in[0];
  const float* wq = (const float*)d_in[1];
  const float* wk = (const float*)d_in[2];
  const float* wv = (const float*)d_in[3];
  const float* wo = (const float*)d_in[4];
  float* out = (float*)d_out;

  char* ws = (char*)d_ws;
  const size_t MB = 1024 * 1024;
  if (ws_size < 57 * MB) return;
  bf16* xb  = (bf16*)(ws + 0 * MB);   // 8 MB
  bf16* wqb = (bf16*)(ws + 8 * MB);   // 2 MB each
  bf16* wkb = (bf16*)(ws + 10 * MB);
  bf16* wvb = (bf16*)(ws + 12 * MB);
  bf16* wob = (bf16*)(ws + 14 * MB);
  bf16* Qb  = (bf16*)(ws + 16 * MB);  // 8 MB each, [B*H][S][64]
  bf16* Kb  = (bf16*)(ws + 24 * MB);
  bf16* Ob  = (bf16*)(ws + 40 * MB);  // 8 MB, [B,S,D]
  float2* rtab = (float2*)(ws + 48 * MB);  // 512 KB RoPE table
  bf16* Vtp = (bf16*)(ws + 49 * MB);  // 8 MB, V transposed [B*H][64][S]

  cvt_all<<<8448, 256, 0, stream>>>(x, wq, wk, wv, wo, xb, wqb, wkb, wvb, wob, rtab);
  proj_qkv<<<dim3(32, 8, 3), 256, 0, stream>>>(xb, wqb, wkb, wvb, Qb, Kb, Vtp, rtab);
  attn<<<dim3(512), 256, 0, stream>>>(Qb, Kb, Vtp, Ob);
  out_proj<<<dim3(32, 8), 256, 0, stream>>>(Ob, wob, out);
}